// Round 5
// baseline (123.054 us; speedup 1.0000x reference)
//
#include <hip/hip_runtime.h>
#include <hip/hip_bf16.h>

#define B_SZ    128
#define IN_F    512
#define OUT_F   128
#define KD      32
#define NC      4096    // OUT_F*KD
#define OUT_COLS 640    // IN_F + OUT_F
#define KC      16      // K-split chunks
#define KCHUNK  32      // IN_F / KC
#define PART_STRIDE (B_SZ * NC)   // 524288 floats per partial buffer
#define MO_PITCH 36     // padded LDS pitch for mo (32 + 4)

// Partial GEMM, K-split 16. Thread owns 4 consecutive cols x 8 rows.
// Per 4-in group: 4x global dwordx4 (T) + 8x wave-uniform ds_read_b128 (x) + 128 FMA.
__global__ __launch_bounds__(256, 4) void gemm_kernel(
    const float* __restrict__ x,            // fp32 [128,512]
    const float* __restrict__ T,            // fp32 [512,4096]
    float* __restrict__ m_part)             // fp32 [16][128*4096]
{
    __shared__ float xs[8 * KCHUNK];        // 1 KB: 8 rows x 32-in chunk
    const int tid = threadIdx.x;
    const int c4  = blockIdx.x * 256 + tid; // float4-column index, 0..1023
    const int b0  = blockIdx.y * 8;
    const int k0  = blockIdx.z * KCHUNK;

    if (tid < 64) {                         // stage x chunk: 8 rows x 8 float4
        int r = tid >> 3, i4 = tid & 7;
        ((float4*)xs)[tid] = *(const float4*)&x[(b0 + r) * IN_F + k0 + i4 * 4];
    }
    __syncthreads();

    float4 acc[8];
    #pragma unroll
    for (int r = 0; r < 8; ++r) acc[r] = make_float4(0.f, 0.f, 0.f, 0.f);

    const float4* T4 = (const float4*)T;    // [512][1024] float4
    #pragma unroll
    for (int g = 0; g < 8; ++g) {           // 8 groups of 4 in-steps
        const int in0 = g * 4;
        float4 tv[4];
        #pragma unroll
        for (int u = 0; u < 4; ++u)
            tv[u] = T4[(k0 + in0 + u) * 1024 + c4];     // coalesced 1KB/wave
        #pragma unroll
        for (int r = 0; r < 8; ++r) {
            const float4 xv = *(const float4*)&xs[r * KCHUNK + in0];  // broadcast b128
            acc[r].x += xv.x*tv[0].x + xv.y*tv[1].x + xv.z*tv[2].x + xv.w*tv[3].x;
            acc[r].y += xv.x*tv[0].y + xv.y*tv[1].y + xv.z*tv[2].y + xv.w*tv[3].y;
            acc[r].z += xv.x*tv[0].z + xv.y*tv[1].z + xv.z*tv[2].z + xv.w*tv[3].z;
            acc[r].w += xv.x*tv[0].w + xv.y*tv[1].w + xv.z*tv[2].w + xv.w*tv[3].w;
        }
    }
    // m layout [o][b][k]: c = 4*c4+cc -> o = c4>>3, k = (c4&7)*4+cc (float4-aligned)
    float* dst = m_part + blockIdx.z * PART_STRIDE + (c4 >> 3) * (B_SZ * KD) + (c4 & 7) * 4;
    #pragma unroll
    for (int r = 0; r < 8; ++r)
        *(float4*)(dst + (b0 + r) * KD) = acc[r];
}

// o_b[j][o] = sum_i exp(-sum_k |m[i,o,k]-m[j,o,k]|) - 1 ; also copies x into out[:, :512]
__global__ __launch_bounds__(1024, 4) void pairwise_kernel(
    const float* __restrict__ x,
    const float* __restrict__ m_part,
    float* __restrict__ out)                // fp32 [128, 640]
{
    __shared__ float mo[B_SZ * MO_PITCH];   // 18 KB, padded
    __shared__ float psum[64 * 16];

    const int tid   = threadIdx.x;
    const int o     = blockIdx.x >> 1;
    const int jhalf = blockIdx.x & 1;

    // fused x -> out[:, 0:512] copy (bit-exact)
    if (tid < 64) {
        int idx = blockIdx.x * 64 + tid;    // float4 index, 16384 total = all of x
        int b = idx >> 7, c4 = idx & 127;
        float4 v = ((const float4*)x)[idx];
        *(float4*)(out + b * OUT_COLS + c4 * 4) = v;
    }

    // stage + reduce the 16 K-partials: thread t owns float4 t of m[:, o, :]
    {
        const float* src = m_part + o * (B_SZ * KD) + tid * 4;
        float4 s = *(const float4*)src;
        #pragma unroll
        for (int p = 1; p < KC; ++p) {
            float4 v = *(const float4*)(src + p * PART_STRIDE);
            s.x += v.x; s.y += v.y; s.z += v.z; s.w += v.w;
        }
        const int i = tid >> 3, k4 = tid & 7;
        *(float4*)&mo[i * MO_PITCH + k4 * 4] = s;
    }
    __syncthreads();

    const int jj  = tid & 63;               // wave-local j
    const int isl = tid >> 6;               // i-slice (0..15), uniform per wave
    const int j   = jhalf * 64 + jj;

    // m_j fragment from padded LDS (8-way b128 conflict, one-time)
    float mj[KD];
    #pragma unroll
    for (int k4 = 0; k4 < 8; ++k4) {
        float4 v = *(const float4*)&mo[j * MO_PITCH + k4 * 4];
        mj[k4*4+0] = v.x; mj[k4*4+1] = v.y; mj[k4*4+2] = v.z; mj[k4*4+3] = v.w;
    }

    float s = 0.f;
    const int i0 = isl * 8;
    for (int i = i0; i < i0 + 8; ++i) {
        float norm = 0.f;
        #pragma unroll
        for (int k4 = 0; k4 < 8; ++k4) {
            float4 v = *(const float4*)&mo[i * MO_PITCH + k4 * 4];  // broadcast, conflict-free
            norm += fabsf(mj[k4*4+0] - v.x) + fabsf(mj[k4*4+1] - v.y)
                  + fabsf(mj[k4*4+2] - v.z) + fabsf(mj[k4*4+3] - v.w);
        }
        s += __expf(-norm);                 // i==j contributes exp(0)=1; the -1 removes it
    }
    psum[jj * 16 + isl] = s;
    __syncthreads();
    if (tid < 64) {
        float tot = 0.f;
        #pragma unroll
        for (int u = 0; u < 16; ++u) tot += psum[tid * 16 + u];
        out[(jhalf * 64 + tid) * OUT_COLS + IN_F + o] = tot - 1.0f;
    }
}

extern "C" void kernel_launch(void* const* d_in, const int* in_sizes, int n_in,
                              void* d_out, int out_size, void* d_ws, size_t ws_size,
                              hipStream_t stream) {
    const float* x = (const float*)d_in[0];
    const float* T = (const float*)d_in[1];
    float* out = (float*)d_out;
    float* m_part = (float*)d_ws;           // 16 * 2 MB = 32 MB of workspace

    gemm_kernel<<<dim3(4, 16, 16), 256, 0, stream>>>(x, T, m_part);
    pairwise_kernel<<<256, 1024, 0, stream>>>(x, m_part, out);
}

// Round 6
// 76.885 us; speedup vs baseline: 1.6005x; 1.6005x over previous
//
#include <hip/hip_runtime.h>

#define B_SZ    128
#define IN_F    512
#define OUT_F   128
#define NC      4096    // OUT_F*KD
#define KD      32
#define OUT_COLS 640    // IN_F + OUT_F
#define MO_PITCH 36     // padded LDS pitch for mo (32 + 4)

typedef __attribute__((ext_vector_type(8))) short  bf16x8;   // MFMA A/B frag (4 VGPRs)
typedef __attribute__((ext_vector_type(4))) float  f32x4;    // MFMA C/D frag

union FragAB { unsigned int u[4]; bf16x8 s; };

// pack two fp32 into two bf16 (truncation — error irrelevant at this tolerance)
static __device__ __forceinline__ unsigned int pack2(float lo, float hi) {
    return (__float_as_uint(lo) >> 16) | (__float_as_uint(hi) & 0xFFFF0000u);
}

// m[128][4096] = x[128,512] @ T[512,4096], bf16 MFMA 16x16x32, fp32 accum.
// Each wave owns one 16(m)x16(n) tile with FULL K=512 -> T read exactly once.
// Grid (64,8) x 256thr = 2048 waves = 2/SIMD full chip.
__global__ __launch_bounds__(256, 2) void gemm_kernel(
    const float* __restrict__ x,            // fp32 [128,512]
    const float* __restrict__ T,            // fp32 [512,4096]
    float* __restrict__ m)                  // fp32 [128][4096]
{
    const int tid  = threadIdx.x;
    const int lane = tid & 63;
    const int w    = tid >> 6;                      // wave 0..3
    const int n0   = (blockIdx.x * 4 + w) * 16;     // n-tile (256 total)
    const int m0   = blockIdx.y * 16;               // m-tile (8 total)
    const int col  = lane & 15;
    const int q    = lane >> 4;                     // quad 0..3

    const float* xrow = x + (m0 + col) * IN_F;      // lane's A row (4 waves share -> L1)
    f32x4 acc = {0.f, 0.f, 0.f, 0.f};

    #pragma unroll 4
    for (int kt = 0; kt < 16; ++kt) {
        const int k0 = kt * 32 + q * 8;             // lane's 8-k slice
        // A frag: x[m0+col][k0..k0+7], 8 consecutive fp32
        const float4 a0 = *(const float4*)(xrow + k0);
        const float4 a1 = *(const float4*)(xrow + k0 + 4);
        FragAB af;
        af.u[0] = pack2(a0.x, a0.y); af.u[1] = pack2(a0.z, a0.w);
        af.u[2] = pack2(a1.x, a1.y); af.u[3] = pack2(a1.z, a1.w);
        // B frag: T[k0+j][n0+col], j=0..7 (rows strided; 256B/wave per inst)
        const float* tb = T + (size_t)k0 * NC + n0 + col;
        const float b0 = tb[0*NC], b1 = tb[1*NC], b2 = tb[2*NC], b3 = tb[3*NC];
        const float b4 = tb[4*NC], b5 = tb[5*NC], b6 = tb[6*NC], b7 = tb[7*NC];
        FragAB bf;
        bf.u[0] = pack2(b0, b1); bf.u[1] = pack2(b2, b3);
        bf.u[2] = pack2(b4, b5); bf.u[3] = pack2(b6, b7);
        acc = __builtin_amdgcn_mfma_f32_16x16x32_bf16(af.s, bf.s, acc, 0, 0, 0);
    }
    // C/D: row = m0 + q*4 + r, col = n0 + (lane&15)
    float* dst = m + (size_t)(m0 + q * 4) * NC + n0 + col;
    dst[0*NC] = acc[0]; dst[1*NC] = acc[1]; dst[2*NC] = acc[2]; dst[3*NC] = acc[3];
}

// o_b[j][o] = sum_i exp(-sum_k |m[i,o,k]-m[j,o,k]|) - 1 ; also copies x into out[:, :512]
__global__ __launch_bounds__(1024, 4) void pairwise_kernel(
    const float* __restrict__ x,
    const float* __restrict__ m,            // fp32 [128][4096] row-major
    float* __restrict__ out)                // fp32 [128, 640]
{
    __shared__ float mo[B_SZ * MO_PITCH];   // 18 KB, padded
    __shared__ float psum[64 * 16];

    const int tid   = threadIdx.x;
    const int o     = blockIdx.x >> 1;
    const int jhalf = blockIdx.x & 1;

    // fused x -> out[:, 0:512] copy (bit-exact)
    if (tid < 64) {
        int idx = blockIdx.x * 64 + tid;    // float4 index, 16384 total = all of x
        int b = idx >> 7, c4 = idx & 127;
        float4 v = ((const float4*)x)[idx];
        *(float4*)(out + b * OUT_COLS + c4 * 4) = v;
    }

    // stage m[:, o*32..o*32+31] -> mo[b][k] (pitch 36). Thread t: b=t>>3, k4=t&7.
    {
        const int b = tid >> 3, k4 = tid & 7;
        float4 v = *(const float4*)(m + (size_t)b * NC + o * KD + k4 * 4);
        *(float4*)&mo[b * MO_PITCH + k4 * 4] = v;
    }
    __syncthreads();

    const int jj  = tid & 63;               // wave-local j
    const int isl = tid >> 6;               // i-slice (0..15), uniform per wave
    const int j   = jhalf * 64 + jj;

    // m_j fragment from padded LDS (one-time, mild conflicts)
    float mj[KD];
    #pragma unroll
    for (int k4 = 0; k4 < 8; ++k4) {
        float4 v = *(const float4*)&mo[j * MO_PITCH + k4 * 4];
        mj[k4*4+0] = v.x; mj[k4*4+1] = v.y; mj[k4*4+2] = v.z; mj[k4*4+3] = v.w;
    }

    float s = 0.f;
    const int i0 = isl * 8;
    for (int i = i0; i < i0 + 8; ++i) {
        float norm = 0.f;
        #pragma unroll
        for (int k4 = 0; k4 < 8; ++k4) {
            float4 v = *(const float4*)&mo[i * MO_PITCH + k4 * 4];  // broadcast, conflict-free
            norm += fabsf(mj[k4*4+0] - v.x) + fabsf(mj[k4*4+1] - v.y)
                  + fabsf(mj[k4*4+2] - v.z) + fabsf(mj[k4*4+3] - v.w);
        }
        s += __expf(-norm);                 // i==j contributes exp(0)=1; the -1 removes it
    }
    psum[jj * 16 + isl] = s;
    __syncthreads();
    if (tid < 64) {
        float tot = 0.f;
        #pragma unroll
        for (int u = 0; u < 16; ++u) tot += psum[tid * 16 + u];
        out[(jhalf * 64 + tid) * OUT_COLS + IN_F + o] = tot - 1.0f;
    }
}

extern "C" void kernel_launch(void* const* d_in, const int* in_sizes, int n_in,
                              void* d_out, int out_size, void* d_ws, size_t ws_size,
                              hipStream_t stream) {
    const float* x = (const float*)d_in[0];
    const float* T = (const float*)d_in[1];
    float* out = (float*)d_out;
    float* m = (float*)d_ws;                // 2 MB of workspace

    gemm_kernel<<<dim3(64, 8), 256, 0, stream>>>(x, T, m);
    pairwise_kernel<<<256, 1024, 0, stream>>>(x, m, out);
}

// Round 7
// 72.873 us; speedup vs baseline: 1.6886x; 1.0551x over previous
//
#include <hip/hip_runtime.h>

#define B_SZ    128
#define IN_F    512
#define OUT_F   128
#define NC      4096    // OUT_F*KD
#define KD      32
#define OUT_COLS 640    // IN_F + OUT_F
#define MO_PITCH 36     // padded LDS pitch for pairwise mo (32 + 4)
#define AS_PITCH 136    // bf16 LDS pitch for K-tiles (128 + 8) -> ~2-way banks, b128-aligned
#define BK      128

typedef __attribute__((ext_vector_type(8))) short  bf16x8;   // MFMA A/B frag
typedef __attribute__((ext_vector_type(4))) float  f32x4;    // MFMA C/D frag

static __device__ __forceinline__ unsigned short f2bfu(float f) {
    return (unsigned short)(__float_as_uint(f) >> 16);   // bf16 truncation
}

// prep: out[:, :512] = x (bit-exact fp32 copy); xb = bf16(x), row-major [128][512]
__global__ __launch_bounds__(256) void prep_kernel(
    const float* __restrict__ x, float* __restrict__ out,
    unsigned short* __restrict__ xb)
{
    int idx = blockIdx.x * 256 + threadIdx.x;       // float4 index, 16384 total
    int b = idx >> 7, c4 = idx & 127;
    float4 v = ((const float4*)x)[idx];
    *(float4*)(out + b * OUT_COLS + c4 * 4) = v;
    ushort4 w;
    w.x = f2bfu(v.x); w.y = f2bfu(v.y); w.z = f2bfu(v.z); w.w = f2bfu(v.w);
    *(ushort4*)(xb + idx * 4) = w;
}

// m[128][4096] = x @ T via bf16 MFMA, all global reads coalesced, frags from LDS.
// Block: M=64 x N=32, K-loop BK=128. 256 blocks x 8 waves; T read exactly once.
__global__ __launch_bounds__(512, 2) void gemm_kernel(
    const unsigned short* __restrict__ xb,  // bf16 [128][512]
    const float* __restrict__ T,            // fp32 [512][4096]
    float* __restrict__ m)                  // fp32 [128][4096]
{
    __shared__ unsigned short as[64 * AS_PITCH];    // 17.0 KB: A tile, [row][k]
    __shared__ unsigned short bs[32 * AS_PITCH];    //  8.5 KB: B^T tile, [n][k]

    const int tid  = threadIdx.x;
    const int lane = tid & 63;
    const int w    = tid >> 6;              // wave 0..7
    const int col  = lane & 15;
    const int q    = lane >> 4;             // quad
    const int n0   = blockIdx.x * 32;
    const int m0   = blockIdx.y * 64;
    const int mt   = w >> 1, nt = w & 1;    // wave's 16x16 tile

    f32x4 acc = {0.f, 0.f, 0.f, 0.f};

    for (int k0 = 0; k0 < IN_F; k0 += BK) {
        __syncthreads();                    // protect LDS from previous iter's readers
        // stage A: xb[m0..m0+63][k0..k0+127] -> as, 1024 x 16B units, coalesced
        #pragma unroll
        for (int p = 0; p < 2; ++p) {
            int u = tid + p * 512;
            int row = u >> 4, o8 = u & 15;
            uint4 v = *(const uint4*)(xb + (m0 + row) * IN_F + k0 + o8 * 8);
            *(uint4*)&as[row * AS_PITCH + o8 * 8] = v;
        }
        // stage B transposed: T[k0+kk][n0..n0+31] -> bs[n][kk]; reads = 128B/row bursts
        #pragma unroll
        for (int p = 0; p < 2; ++p) {
            int u = tid + p * 512;          // 0..1023
            int kk = u >> 3, nq = u & 7;
            float4 v = *(const float4*)(T + (size_t)(k0 + kk) * NC + n0 + nq * 4);
            int nb = nq * 4;
            bs[(nb + 0) * AS_PITCH + kk] = f2bfu(v.x);
            bs[(nb + 1) * AS_PITCH + kk] = f2bfu(v.y);
            bs[(nb + 2) * AS_PITCH + kk] = f2bfu(v.z);
            bs[(nb + 3) * AS_PITCH + kk] = f2bfu(v.w);
        }
        __syncthreads();
        #pragma unroll
        for (int kt = 0; kt < 4; ++kt) {
            const int krel = kt * 32 + q * 8;
            bf16x8 af = *(const bf16x8*)&as[(mt * 16 + col) * AS_PITCH + krel];
            bf16x8 bf = *(const bf16x8*)&bs[(nt * 16 + col) * AS_PITCH + krel];
            acc = __builtin_amdgcn_mfma_f32_16x16x32_bf16(af, bf, acc, 0, 0, 0);
        }
    }
    // C/D: row = q*4 + reg, col = lane&15 (m89/m91-verified mapping)
    float* dst = m + (size_t)(m0 + mt * 16 + q * 4) * NC + n0 + nt * 16 + col;
    dst[0 * NC] = acc[0]; dst[1 * NC] = acc[1];
    dst[2 * NC] = acc[2]; dst[3 * NC] = acc[3];
}

// o_b[j][o] = sum_i exp(-sum_k |m[i,o,k]-m[j,o,k]|) - 1
__global__ __launch_bounds__(1024, 4) void pairwise_kernel(
    const float* __restrict__ m,            // fp32 [128][4096] row-major
    float* __restrict__ out)                // fp32 [128, 640]
{
    __shared__ float mo[B_SZ * MO_PITCH];   // 18 KB, padded
    __shared__ float psum[64 * 16];

    const int tid   = threadIdx.x;
    const int o     = blockIdx.x >> 1;
    const int jhalf = blockIdx.x & 1;

    // stage m[:, o*32..o*32+31] -> mo[b][k] (pitch 36). Thread t: b=t>>3, k4=t&7.
    {
        const int b = tid >> 3, k4 = tid & 7;
        float4 v = *(const float4*)(m + (size_t)b * NC + o * KD + k4 * 4);
        *(float4*)&mo[b * MO_PITCH + k4 * 4] = v;
    }
    __syncthreads();

    const int jj  = tid & 63;               // wave-local j
    const int isl = tid >> 6;               // i-slice (0..15), uniform per wave
    const int j   = jhalf * 64 + jj;

    float mj[KD];
    #pragma unroll
    for (int k4 = 0; k4 < 8; ++k4) {
        float4 v = *(const float4*)&mo[j * MO_PITCH + k4 * 4];
        mj[k4*4+0] = v.x; mj[k4*4+1] = v.y; mj[k4*4+2] = v.z; mj[k4*4+3] = v.w;
    }

    float s = 0.f;
    const int i0 = isl * 8;
    for (int i = i0; i < i0 + 8; ++i) {
        float norm = 0.f;
        #pragma unroll
        for (int k4 = 0; k4 < 8; ++k4) {
            float4 v = *(const float4*)&mo[i * MO_PITCH + k4 * 4];  // broadcast, conflict-free
            norm += fabsf(mj[k4*4+0] - v.x) + fabsf(mj[k4*4+1] - v.y)
                  + fabsf(mj[k4*4+2] - v.z) + fabsf(mj[k4*4+3] - v.w);
        }
        s += __expf(-norm);                 // i==j contributes exp(0)=1; the -1 removes it
    }
    psum[jj * 16 + isl] = s;
    __syncthreads();
    if (tid < 64) {
        float tot = 0.f;
        #pragma unroll
        for (int u = 0; u < 16; ++u) tot += psum[tid * 16 + u];
        out[(jhalf * 64 + tid) * OUT_COLS + IN_F + o] = tot - 1.0f;
    }
}

extern "C" void kernel_launch(void* const* d_in, const int* in_sizes, int n_in,
                              void* d_out, int out_size, void* d_ws, size_t ws_size,
                              hipStream_t stream) {
    const float* x = (const float*)d_in[0];
    const float* T = (const float*)d_in[1];
    float* out = (float*)d_out;
    float* m = (float*)d_ws;                              // 2 MB
    unsigned short* xb = (unsigned short*)((char*)d_ws + (2u << 20));  // 128 KB

    prep_kernel<<<64, 256, 0, stream>>>(x, out, xb);
    gemm_kernel<<<dim3(128, 2), 512, 0, stream>>>(xb, T, m);
    pairwise_kernel<<<256, 1024, 0, stream>>>(m, out);
}